// Round 3
// baseline (271.798 us; speedup 1.0000x reference)
//
#include <hip/hip_runtime.h>

#define NFFT 1024
#define TPB 256
#define ROWS 4  // rows per wave, software-pipelined

// ---------- complex helpers ----------
__device__ __forceinline__ float2 cmul(float2 a, float2 b) {
  return make_float2(fmaf(a.x, b.x, -a.y * b.y), fmaf(a.x, b.y, a.y * b.x));
}
__device__ __forceinline__ float2 cadd(float2 a, float2 b) { return make_float2(a.x + b.x, a.y + b.y); }
__device__ __forceinline__ float2 csub(float2 a, float2 b) { return make_float2(a.x - b.x, a.y - b.y); }

// y_k = sum_r v_r * e^{-2*pi*i*k*r/4}
__device__ __forceinline__ void dft4(const float2 v[4], float2 y[4]) {
  float2 s02 = cadd(v[0], v[2]), d02 = csub(v[0], v[2]);
  float2 s13 = cadd(v[1], v[3]), d13 = csub(v[1], v[3]);
  y[0] = cadd(s02, s13);
  y[2] = csub(s02, s13);
  y[1] = make_float2(d02.x + d13.y, d02.y - d13.x);  // d02 + (-i)*d13
  y[3] = make_float2(d02.x - d13.y, d02.y + d13.x);  // d02 + (+i)*d13
}

// ---------- DPP quad shuffles ----------
__device__ __forceinline__ float dpp_xor2(float x) {
  return __int_as_float(__builtin_amdgcn_update_dpp(0, __float_as_int(x), 0x4E, 0xF, 0xF, true));
}
__device__ __forceinline__ float dpp_xor1(float x) {
  return __int_as_float(__builtin_amdgcn_update_dpp(0, __float_as_int(x), 0xB1, 0xF, 0xF, true));
}

// ---------- in-lane 16-point FFT ----------
// Output: slot s holds Z[KOF(s)], KOF(s) = (s>>2) | ((s&3)<<2). Twiddles compile-time.
__device__ __forceinline__ void fft16(float2 z[16]) {
  float2 g[16];
  #pragma unroll
  for (int c0 = 0; c0 < 4; ++c0) {
    float2 v[4] = {z[c0], z[c0 + 4], z[c0 + 8], z[c0 + 12]};
    float2 y[4];
    dft4(v, y);
    g[4 * c0 + 0] = y[0]; g[4 * c0 + 1] = y[1]; g[4 * c0 + 2] = y[2]; g[4 * c0 + 3] = y[3];
  }
  const float C1 = 0.92387953251128674f, S1 = 0.38268343236508978f, R = 0.70710678118654752f;
  g[5]  = cmul(g[5],  make_float2( C1, -S1));
  g[6]  = cmul(g[6],  make_float2(  R,  -R));
  g[7]  = cmul(g[7],  make_float2( S1, -C1));
  g[9]  = cmul(g[9],  make_float2(  R,  -R));
  g[10] = make_float2(g[10].y, -g[10].x);
  g[11] = cmul(g[11], make_float2( -R,  -R));
  g[13] = cmul(g[13], make_float2( S1, -C1));
  g[14] = cmul(g[14], make_float2( -R,  -R));
  g[15] = cmul(g[15], make_float2(-C1,  S1));
  #pragma unroll
  for (int k0 = 0; k0 < 4; ++k0) {
    float2 v[4] = {g[k0], g[4 + k0], g[8 + k0], g[12 + k0]};
    float2 y[4];
    dft4(v, y);
    z[4 * k0 + 0] = y[0]; z[4 * k0 + 1] = y[1]; z[4 * k0 + 2] = y[2]; z[4 * k0 + 3] = y[3];
  }
}

// Multiply slot-ordered spectrum by u^kappa (kappa = KOF(slot)), via running powers.
__device__ __forceinline__ void twiddle_apply(float2 z[16], float2 u) {
  float2 w = u;
  #pragma unroll
  for (int k = 1; k < 16; ++k) {
    const int s = ((k & 3) << 2) | (k >> 2);
    z[s] = cmul(z[s], w);
    w = cmul(w, u);
  }
}

__device__ __forceinline__ void loadrow(float2 z[16], const float2* __restrict__ src, int lane) {
  #pragma unroll
  for (int c = 0; c < 16; ++c) z[c] = src[lane + 64 * c];  // 512B contiguous per instr
}

// One full 1024-pt row: fft16 -> W1024 twiddle -> in-place LDS transpose
// (conflict-free XOR swizzle, wave-private, no s_barrier) -> fft16 -> W64
// twiddle -> cross-quad radix-4 via DPP -> nontemporal coalesced-segment stores.
__device__ __forceinline__ void procrow(float2 z[16], float2* __restrict__ buf,
                                        float2 u1, float2 u2, int lane,
                                        float2* __restrict__ dst) {
  fft16(z);
  twiddle_apply(z, u1);

  // in-place transpose: writer lane n'=4m+p, slot kap -> m*64 + ((p+4kap) ^ ((m&3)<<2))
  //                     reader lane l2, reg mm       -> mm*64 + (l2 ^ ((mm&3)<<2))
  // per-16-lane phase both sides hit all 16 bank-pairs exactly once (verified 0 conflicts r2)
  const int m = lane >> 2, p = lane & 3;
  #pragma unroll
  for (int s = 0; s < 16; ++s) {
    const int kap = (s >> 2) | ((s & 3) << 2);
    buf[m * 64 + ((p + 4 * kap) ^ ((m & 3) << 2))] = z[s];
  }
  asm volatile("s_waitcnt lgkmcnt(0)" ::: "memory");
  __builtin_amdgcn_sched_barrier(0);
  #pragma unroll
  for (int mm = 0; mm < 16; ++mm) z[mm] = buf[mm * 64 + (lane ^ ((mm & 3) << 2))];

  fft16(z);
  twiddle_apply(z, u2);

  // final radix-4 across quad lanes via DPP
  const float sgn1 = (lane & 2) ? -1.0f : 1.0f;
  const float sgn2 = (lane & 1) ? -1.0f : 1.0f;
  const bool tw3 = ((lane & 3) == 3);
  #pragma unroll
  for (int s = 0; s < 16; ++s) {
    float px = dpp_xor2(z[s].x), py = dpp_xor2(z[s].y);
    float ax = fmaf(sgn1, z[s].x, px), ay = fmaf(sgn1, z[s].y, py);
    float bx = tw3 ? ay : ax;
    float by = tw3 ? -ax : ay;
    float qx = dpp_xor1(bx), qy = dpp_xor1(by);
    z[s].x = fmaf(sgn2, bx, qx);
    z[s].y = fmaf(sgn2, by, qy);
  }

  // store X[kap + 16*t + 256*ur(p)]; 4x128B segments per instr; nontemporal
  const int kap = lane >> 2;
  const int ur = ((p & 1) << 1) | (p >> 1);  // bitrev2(p)
  float2* __restrict__ orow = dst + kap + 256 * ur;
  #pragma unroll
  for (int s = 0; s < 16; ++s) {
    const int t = (s >> 2) | ((s & 3) << 2);
    __builtin_nontemporal_store(*reinterpret_cast<const double*>(&z[s]),
                                reinterpret_cast<double*>(orow + 16 * t));
  }
}

__global__ __launch_bounds__(TPB, 4) void fft1024_kernel(const float* __restrict__ in,
                                                         float* __restrict__ out,
                                                         int nrows) {
  __shared__ float2 lds[TPB / 64][NFFT];  // 8 KB per wave, wave-private, reused across ROWS
  const int wv = threadIdx.x >> 6;
  const int lane = threadIdx.x & 63;
  const int r0 = (blockIdx.x * (TPB / 64) + wv) * ROWS;
  if (r0 >= nrows) return;

  const float2* __restrict__ xin = reinterpret_cast<const float2*>(in) + (size_t)r0 * NFFT;
  float2* __restrict__ xout = reinterpret_cast<float2*>(out) + (size_t)r0 * NFFT;
  float2* buf = lds[wv];

  // row-invariant twiddle bases (hoisted: 2 sincos per wave total)
  float sn, cs;
  __sincosf((float)lane * (-6.2831853071795864769f / 1024.0f), &sn, &cs);
  const float2 u1 = make_float2(cs, sn);
  __sincosf((float)(lane & 3) * (-6.2831853071795864769f / 64.0f), &sn, &cs);
  const float2 u2 = make_float2(cs, sn);

  // 4 rows, 2 register buffers, software-pipelined: next row's loads are in
  // flight while current row computes (hides ~900cyc HBM latency under ~2500cyc FFT)
  float2 A[16], B[16];
  loadrow(A, xin, lane);
  loadrow(B, xin + NFFT, lane);
  procrow(A, buf, u1, u2, lane, xout);
  loadrow(A, xin + 2 * NFFT, lane);
  procrow(B, buf, u1, u2, lane, xout + NFFT);
  loadrow(B, xin + 3 * NFFT, lane);
  procrow(A, buf, u1, u2, lane, xout + 2 * NFFT);
  procrow(B, buf, u1, u2, lane, xout + 3 * NFFT);
}

extern "C" void kernel_launch(void* const* d_in, const int* in_sizes, int n_in,
                              void* d_out, int out_size, void* d_ws, size_t ws_size,
                              hipStream_t stream) {
  const float* x = (const float*)d_in[0];
  float* out = (float*)d_out;
  const int rows = in_sizes[0] / (2 * NFFT);  // 16384 rows of 1024 complex
  const int rpb = (TPB / 64) * ROWS;          // 16 rows per block
  const int blocks = (rows + rpb - 1) / rpb;  // 1024 blocks
  fft1024_kernel<<<blocks, TPB, 0, stream>>>(x, out, rows);
}

// Round 4
// 229.443 us; speedup vs baseline: 1.1846x; 1.1846x over previous
//
#include <hip/hip_runtime.h>

#define NFFT 1024
#define TPB 256  // 4 waves per block, one 1024-pt row per wave

// ---------- complex helpers ----------
__device__ __forceinline__ float2 cmul(float2 a, float2 b) {
  return make_float2(fmaf(a.x, b.x, -a.y * b.y), fmaf(a.x, b.y, a.y * b.x));
}
__device__ __forceinline__ float2 cadd(float2 a, float2 b) { return make_float2(a.x + b.x, a.y + b.y); }
__device__ __forceinline__ float2 csub(float2 a, float2 b) { return make_float2(a.x - b.x, a.y - b.y); }

// y_k = sum_r v_r * e^{-2*pi*i*k*r/4}
__device__ __forceinline__ void dft4(const float2 v[4], float2 y[4]) {
  float2 s02 = cadd(v[0], v[2]), d02 = csub(v[0], v[2]);
  float2 s13 = cadd(v[1], v[3]), d13 = csub(v[1], v[3]);
  y[0] = cadd(s02, s13);
  y[2] = csub(s02, s13);
  y[1] = make_float2(d02.x + d13.y, d02.y - d13.x);  // d02 + (-i)*d13
  y[3] = make_float2(d02.x - d13.y, d02.y + d13.x);  // d02 + (+i)*d13
}

// ---------- DPP quad shuffles ----------
__device__ __forceinline__ float dpp_xor2(float x) {
  return __int_as_float(__builtin_amdgcn_update_dpp(0, __float_as_int(x), 0x4E, 0xF, 0xF, true));
}
__device__ __forceinline__ float dpp_xor1(float x) {
  return __int_as_float(__builtin_amdgcn_update_dpp(0, __float_as_int(x), 0xB1, 0xF, 0xF, true));
}

// ---------- in-lane 16-point FFT (verified r1-r3) ----------
// Output: slot s holds Z[KOF(s)], KOF(s) = (s>>2) | ((s&3)<<2). Twiddles compile-time.
__device__ __forceinline__ void fft16(float2 z[16]) {
  float2 g[16];
  #pragma unroll
  for (int c0 = 0; c0 < 4; ++c0) {
    float2 v[4] = {z[c0], z[c0 + 4], z[c0 + 8], z[c0 + 12]};
    float2 y[4];
    dft4(v, y);
    g[4 * c0 + 0] = y[0]; g[4 * c0 + 1] = y[1]; g[4 * c0 + 2] = y[2]; g[4 * c0 + 3] = y[3];
  }
  const float C1 = 0.92387953251128674f, S1 = 0.38268343236508978f, R = 0.70710678118654752f;
  g[5]  = cmul(g[5],  make_float2( C1, -S1));
  g[6]  = cmul(g[6],  make_float2(  R,  -R));
  g[7]  = cmul(g[7],  make_float2( S1, -C1));
  g[9]  = cmul(g[9],  make_float2(  R,  -R));
  g[10] = make_float2(g[10].y, -g[10].x);
  g[11] = cmul(g[11], make_float2( -R,  -R));
  g[13] = cmul(g[13], make_float2( S1, -C1));
  g[14] = cmul(g[14], make_float2( -R,  -R));
  g[15] = cmul(g[15], make_float2(-C1,  S1));
  #pragma unroll
  for (int k0 = 0; k0 < 4; ++k0) {
    float2 v[4] = {g[k0], g[4 + k0], g[8 + k0], g[12 + k0]};
    float2 y[4];
    dft4(v, y);
    z[4 * k0 + 0] = y[0]; z[4 * k0 + 1] = y[1]; z[4 * k0 + 2] = y[2]; z[4 * k0 + 3] = y[3];
  }
}

// Multiply slot-ordered spectrum by u^kappa (kappa = KOF(slot)), via running powers.
__device__ __forceinline__ void twiddle_apply(float2 z[16], float2 u) {
  float2 w = u;
  #pragma unroll
  for (int k = 1; k < 16; ++k) {
    const int s = ((k & 3) << 2) | (k >> 2);
    z[s] = cmul(z[s], w);
    w = cmul(w, u);
  }
}

// One wave per 1024-pt row. Global side is pure float4 streaming (1KB/instr);
// FFT lane-mapping is served entirely from LDS with conflict-free swizzles.
__global__ __launch_bounds__(TPB, 4) void fft1024_kernel(const float* __restrict__ in,
                                                         float* __restrict__ out,
                                                         int nrows) {
  __shared__ __align__(16) float2 lds[TPB / 64][NFFT];  // 8 KB per wave, wave-private
  const int wv = threadIdx.x >> 6;
  const int lane = threadIdx.x & 63;
  const int row = blockIdx.x * (TPB / 64) + wv;
  if (row >= nrows) return;

  const float4* __restrict__ xin4 = reinterpret_cast<const float4*>(in) + (size_t)row * (NFFT / 2);
  float4* __restrict__ xout4 = reinterpret_cast<float4*>(out) + (size_t)row * (NFFT / 2);
  float2* buf = lds[wv];

  // ---- stage-in: 8x float4 coalesced loads (1KB/instr) -> LDS plain layout
  float4 v4[8];
  #pragma unroll
  for (int j = 0; j < 8; ++j) v4[j] = xin4[lane + 64 * j];
  #pragma unroll
  for (int j = 0; j < 8; ++j)
    *reinterpret_cast<float4*>(&buf[2 * lane + 128 * j]) = v4[j];  // ds_write_b128, conflict-free
  asm volatile("s_waitcnt lgkmcnt(0)" ::: "memory");
  __builtin_amdgcn_sched_barrier(0);

  // ---- gather FFT mapping: z[c] = x[lane + 64c] (contiguous b64 reads, free)
  float2 z[16];
  #pragma unroll
  for (int c = 0; c < 16; ++c) z[c] = buf[lane + 64 * c];
  asm volatile("s_waitcnt lgkmcnt(0)" ::: "memory");
  __builtin_amdgcn_sched_barrier(0);

  // ---- phase 1
  fft16(z);
  float sn, cs;
  __sincosf((float)lane * (-6.2831853071795864769f / 1024.0f), &sn, &cs);
  twiddle_apply(z, make_float2(cs, sn));

  // ---- transpose (r2-verified conflict-free XOR swizzle, wave-private, no s_barrier)
  const int m = lane >> 2, p = lane & 3;
  #pragma unroll
  for (int s = 0; s < 16; ++s) {
    const int kap = (s >> 2) | ((s & 3) << 2);
    buf[m * 64 + ((p + 4 * kap) ^ ((m & 3) << 2))] = z[s];
  }
  asm volatile("s_waitcnt lgkmcnt(0)" ::: "memory");
  __builtin_amdgcn_sched_barrier(0);
  #pragma unroll
  for (int mm = 0; mm < 16; ++mm) z[mm] = buf[mm * 64 + (lane ^ ((mm & 3) << 2))];
  asm volatile("s_waitcnt lgkmcnt(0)" ::: "memory");
  __builtin_amdgcn_sched_barrier(0);

  // ---- phase 2
  fft16(z);
  __sincosf((float)p * (-6.2831853071795864769f / 64.0f), &sn, &cs);
  twiddle_apply(z, make_float2(cs, sn));

  // ---- final radix-4 across quad lanes via DPP
  const float sgn1 = (lane & 2) ? -1.0f : 1.0f;
  const float sgn2 = (lane & 1) ? -1.0f : 1.0f;
  const bool tw3 = ((lane & 3) == 3);
  #pragma unroll
  for (int s = 0; s < 16; ++s) {
    float px = dpp_xor2(z[s].x), py = dpp_xor2(z[s].y);
    float ax = fmaf(sgn1, z[s].x, px), ay = fmaf(sgn1, z[s].y, py);
    float bx = tw3 ? ay : ax;
    float by = tw3 ? -ax : ay;
    float qx = dpp_xor1(bx), qy = dpp_xor1(by);
    z[s].x = fmaf(sgn2, bx, qx);
    z[s].y = fmaf(sgn2, by, qy);
  }

  // ---- stage-out: write swizzled linear layout, then float4 streaming stores.
  // idx = kap + 16t + 256ur (bits [3:0]=kap, [7:4]=t, [9:8]=ur); S(idx)=idx^(ur<<4).
  // Per write instr: residues kap + 16*((t&3)^ur) = 64 distinct -> conflict-free.
  const int kap = lane >> 2;
  const int ur = ((p & 1) << 1) | (p >> 1);  // bitrev2(p)
  const int x16 = ur << 4;
  #pragma unroll
  for (int s = 0; s < 16; ++s) {
    const int t = (s >> 2) | ((s & 3) << 2);
    const int idx = kap + 16 * t + 256 * ur;
    buf[idx ^ x16] = z[s];
  }
  asm volatile("s_waitcnt lgkmcnt(0)" ::: "memory");
  __builtin_amdgcn_sched_barrier(0);
  // reader: i = 2lane+128j -> (i>>8)&3 == j>>1 (const per j); b128 contiguous per instr
  #pragma unroll
  for (int j = 0; j < 8; ++j) {
    float4 w = *reinterpret_cast<const float4*>(&buf[(2 * lane + 128 * j) ^ ((j >> 1) << 4)]);
    xout4[lane + 64 * j] = w;  // global_store_dwordx4, 1KB/instr contiguous
  }
}

extern "C" void kernel_launch(void* const* d_in, const int* in_sizes, int n_in,
                              void* d_out, int out_size, void* d_ws, size_t ws_size,
                              hipStream_t stream) {
  const float* x = (const float*)d_in[0];
  float* out = (float*)d_out;
  const int rows = in_sizes[0] / (2 * NFFT);  // 16384 rows of 1024 complex
  const int rpb = TPB / 64;
  const int blocks = (rows + rpb - 1) / rpb;
  fft1024_kernel<<<blocks, TPB, 0, stream>>>(x, out, rows);
}